// Round 1
// 283.553 us; speedup vs baseline: 1.0596x; 1.0596x over previous
//
#include <hip/hip_runtime.h>

#define HIDDEN 1280
#define QOUT   1920
#define QSIZE  1280
#define KVSIZE 320
#define NHEAD  16
#define NKV    4
#define DH     80
#define SEQ    2048
#define BATCH  4
#define MTOT   (BATCH * SEQ)   // 8192
#define NT64   (SEQ / 64)      // 32 key tiles
#define KTILE_ELEMS 6144       // 64 x 96 (swizzled chunk layout)
#define VTILE_ELEMS 5120       // 80 d x 64 key (XOR-chunk swizzled)

typedef __attribute__((ext_vector_type(8))) short bf16x8;
typedef __attribute__((ext_vector_type(4))) short bf16x4;
typedef __attribute__((ext_vector_type(4))) float f32x4;

__device__ __forceinline__ unsigned short f2bf(float x) {
  union { float f; unsigned u; } v; v.f = x;
  unsigned r = v.u + 0x7fffu + ((v.u >> 16) & 1u);
  return (unsigned short)(r >> 16);
}

// round-half-up pack of two f32 -> bf16x2 (lo=a, hi=b)
__device__ __forceinline__ unsigned packbf(float a, float b) {
  union { float f; unsigned u; } ua, ub;
  ua.f = a; ub.f = b;
  return __builtin_amdgcn_perm(ub.u + 0x8000u, ua.u + 0x8000u, 0x07060302u);
}

// truncating pack (1 v_perm): fine for P (downward bias cancels via l-normalization)
__device__ __forceinline__ unsigned packbf_t(float a, float b) {
  union { float f; unsigned u; } ua, ub;
  ua.f = a; ub.f = b;
  return __builtin_amdgcn_perm(ub.u, ua.u, 0x07060302u);
}

__device__ __forceinline__ float exp2x(float x) {
#if __has_builtin(__builtin_amdgcn_exp2f)
  return __builtin_amdgcn_exp2f(x);
#else
  return exp2f(x);
#endif
}

__device__ __forceinline__ void async_copy16(const void* g, void* lds) {
  __builtin_amdgcn_global_load_lds(
      (const __attribute__((address_space(1))) unsigned int*)g,
      (__attribute__((address_space(3))) unsigned int*)lds, 16, 0, 0);
}

// ---------------- fused prep: 3x fp32->bf16 cast + colscale ----------------
#define HSB   (MTOT * HIDDEN / 4 / 256)        // 10240
#define QWB   (QOUT * HIDDEN / 4 / 256)        // 2400
#define OWB   (HIDDEN * QSIZE / 4 / 256)       // 1600
__global__ __launch_bounds__(256) void prep_k(const float* __restrict__ hs,
                                              const float* __restrict__ qkv_w,
                                              const float* __restrict__ o_w,
                                              const float* __restrict__ scaling,
                                              unsigned short* __restrict__ hs_bf,
                                              unsigned short* __restrict__ qkvw_bf,
                                              unsigned short* __restrict__ ow_bf,
                                              float* __restrict__ cs) {
  const int bid = blockIdx.x, tid = threadIdx.x;
  const float* src; unsigned short* dst; int i;
  if (bid < HSB)            { src = hs;    dst = hs_bf;   i = bid * 256 + tid; }
  else if (bid < HSB + QWB) { src = qkv_w; dst = qkvw_bf; i = (bid - HSB) * 256 + tid; }
  else if (bid < HSB + QWB + OWB) { src = o_w; dst = ow_bf; i = (bid - HSB - QWB) * 256 + tid; }
  else {
    int n = (bid - HSB - QWB - OWB) * 256 + tid;
    if (n < QOUT) {
      float v = 1.0f;
      if (n < QSIZE) {
        float x = scaling[n % DH];
        float sp = (x > 20.f) ? x : log1pf(__expf(x));
        v = 1.442695041f * 1.442695041f * 0.11180339887f * sp;  // incl. log2(e)
      }
      cs[n] = v;
    }
    return;
  }
  float4 v = ((const float4*)src)[i];
  ushort4 o;
  o.x = f2bf(v.x); o.y = f2bf(v.y); o.z = f2bf(v.z); o.w = f2bf(v.w);
  ((ushort4*)dst)[i] = o;
}

// ---------------- 256x128 bf16 MFMA GEMM, BK=64, 512 threads ----------------
template <bool OUT_BF16, bool USE_SCALE>
__global__ __launch_bounds__(512) void gemm_bt(const unsigned short* __restrict__ A,
                                               const unsigned short* __restrict__ Bt,
                                               const float* __restrict__ bias,
                                               const float* __restrict__ colscale,
                                               void* __restrict__ Cout,
                                               int M, int N, int K) {
  __shared__ unsigned short As[256 * 64];
  __shared__ unsigned short Bs[128 * 64];
  const int tid  = threadIdx.x;
  const int wave = tid >> 6, lane = tid & 63;
  const int r = lane & 15, quad = lane >> 4;
  const int xm = r & 7;
  const int m0 = blockIdx.y * 256, n0 = blockIdx.x * 128;
  const int rm = (wave >> 1) * 64, cn = (wave & 1) * 64;

  f32x4 acc[4][4];
#pragma unroll
  for (int i = 0; i < 4; ++i)
#pragma unroll
    for (int j = 0; j < 4; ++j) acc[i][j] = f32x4{0.f, 0.f, 0.f, 0.f};

  for (int k0 = 0; k0 < K; k0 += 64) {
    __syncthreads();
#pragma unroll
    for (int j = 0; j < 4; ++j) {                 // As: 2048 chunks
      const int c = tid + j * 512;
      const int row = c >> 3, sp = c & 7;
      const int sd = (sp ^ (row & 7)) * 8;
      async_copy16(A + (size_t)(m0 + row) * K + k0 + sd, &As[c * 8]);
    }
#pragma unroll
    for (int j = 0; j < 2; ++j) {                 // Bs: 1024 chunks
      const int c = tid + j * 512;
      const int row = c >> 3, sp = c & 7;
      const int sd = (sp ^ (row & 7)) * 8;
      async_copy16(Bt + (size_t)(n0 + row) * K + k0 + sd, &Bs[c * 8]);
    }
    __syncthreads();
#pragma unroll
    for (int kk = 0; kk < 2; ++kk) {
      bf16x8 af[4], bfr[4];
#pragma unroll
      for (int mi = 0; mi < 4; ++mi)
        af[mi] = *(const bf16x8*)&As[(rm + mi * 16 + r) * 64 + ((kk * 4 + quad) ^ xm) * 8];
#pragma unroll
      for (int ni = 0; ni < 4; ++ni)
        bfr[ni] = *(const bf16x8*)&Bs[(cn + ni * 16 + r) * 64 + ((kk * 4 + quad) ^ xm) * 8];
#pragma unroll
      for (int mi = 0; mi < 4; ++mi)
#pragma unroll
        for (int ni = 0; ni < 4; ++ni)
          acc[mi][ni] = __builtin_amdgcn_mfma_f32_16x16x32_bf16(af[mi], bfr[ni], acc[mi][ni], 0, 0, 0);
    }
  }

#pragma unroll
  for (int ni = 0; ni < 4; ++ni) {
    const int n = n0 + cn + ni * 16 + r;
    const float bn = bias[n];
    const float sc = USE_SCALE ? colscale[n] : 1.0f;
#pragma unroll
    for (int mi = 0; mi < 4; ++mi) {
#pragma unroll
      for (int reg = 0; reg < 4; ++reg) {
        const int m = m0 + rm + mi * 16 + quad * 4 + reg;
        const float v = (acc[mi][ni][reg] + bn) * sc;
        if (OUT_BF16)
          ((unsigned short*)Cout)[(size_t)m * N + n] = f2bf(v);
        else
          ((float*)Cout)[(size_t)m * N + n] = v;
      }
    }
  }
}

// ---------------- merged K pack (swizzled + PAIR-INTERLEAVED rows) + V pack ----
// K rows are permuted so that two consecutive 16-key QK tiles deliver each lane
// keys quad*8+{0..7} of a 32-key group -- exactly the B-fragment layout of
// mfma_16x16x32, letting PV run at full-K rate with P still register-resident.
//   Kp row -> physical key: (row>>5)*32 + ((row>>2)&3)*8 + ((row>>4)&1)*4 + (row&3)
// V image: [80 d][64 key], 8-key chunks XOR-swizzled by (d&7) so the x32
// A-fragment b128 reads sit at the 8-touch/bank floor (old b64 reads at stride
// 72 were 1 conflict-cycle each = the entire 6.29M SQ_LDS_BANK_CONFLICT).
__global__ __launch_bounds__(256) void kvpack(const unsigned short* __restrict__ qkv,
                                              unsigned short* __restrict__ Kp,
                                              unsigned short* __restrict__ Vp) {
  const int st = blockIdx.x, kvh = blockIdx.y, b = blockIdx.z;
  const int tid = threadIdx.x;
  unsigned short* kout = Kp + (size_t)((b * NKV + kvh) * NT64 + st) * KTILE_ELEMS;
#pragma unroll
  for (int j = 0; j < 3; ++j) {
    int c = tid + j * 256;                  // phys chunk 0..767
    int row = c / 12, cir = c - row * 12;
    int kk = cir >> 2, sp = cir & 3;
    int sd = sp ^ ((row >> 1) & 3);
    int d0 = kk * 32 + sd * 8;
    // pair-interleave permutation: Kp row -> source key
    int skey = (row >> 5) * 32 + ((row >> 2) & 3) * 8 + ((row >> 4) & 1) * 4 + (row & 3);
    uint4 v = {0, 0, 0, 0};
    if (d0 < DH)
      v = *(const uint4*)&qkv[(size_t)(b * SEQ + st * 64 + skey) * QOUT +
                              QSIZE + kvh * DH + d0];
    *(uint4*)&kout[row * 96 + kk * 32 + sp * 8] = v;
  }
  // V transpose -> [80 d][64 key], key-chunk XOR swizzle by d&7
  __shared__ unsigned short tile[64][88];
  for (int c = tid; c < 640; c += 256) {
    int row = c / 10, seg = c % 10;
    uint4 v = *(const uint4*)&qkv[(size_t)(b * SEQ + st * 64 + row) * QOUT +
                                  QSIZE + KVSIZE + kvh * DH + seg * 8];
    *(uint4*)&tile[row][seg * 8] = v;
  }
  __syncthreads();
  unsigned short* vout = Vp + (size_t)((b * NKV + kvh) * NT64 + st) * VTILE_ELEMS;
  for (int c = tid; c < 5120; c += 256) {
    int d = c >> 6, key = c & 63;
    vout[d * 64 + (key ^ ((d & 7) << 3))] = tile[key][d];
  }
}

// ---------------- flash attention v4: full-rate x32 PV from registers --------
// QK: 16x16x32 S^T; pair-interleaved K rows make two consecutive 16-key tiles
// give lane (r,quad) exactly keys quad*8+{0..7} of a 32-key group = the
// mfma_16x16x32 B-fragment. P packs to bf16x8 in-lane: no LDS, no sync, and PV
// now runs at the same per-FLOP rate as QK (was 16x16x16 = half rate).
// l still free via 16 ones-rows appended to Vs (d 80..95, swizzle-invariant).
__global__ __launch_bounds__(256, 2) void attn(const unsigned short* __restrict__ qkv,
                                               const unsigned short* __restrict__ Kp,
                                               const unsigned short* __restrict__ Vp,
                                               unsigned short* __restrict__ att) {
  const int qt = blockIdx.x, h = blockIdx.y, b = blockIdx.z;
  const int kvh = h >> 2;
  const int tid = threadIdx.x;
  const int wave = tid >> 6, lane = tid & 63;
  const int r = lane & 15, quad = lane >> 4;
  const int sq8 = (quad ^ ((r >> 1) & 3)) * 8;

  __shared__ unsigned short Ks[64 * 96];     // swizzled image, b128 bank floor
  __shared__ unsigned short Vs[96 * 64];     // [d][key] chunk-swizzled; rows 80..95 = 1.0

  // one-time ones rows (DMA only ever writes rows 0..79); all-ones is
  // invariant under the key-chunk swizzle.
  {
    const uint4 ones = {0x3F803F80u, 0x3F803F80u, 0x3F803F80u, 0x3F803F80u};
    for (int c = tid; c < 128; c += 256)
      *(uint4*)&Vs[80 * 64 + c * 8] = ones;
  }

  // Q fragments straight from global (once). d>=80 lanes read neighbor data
  // that K's zero-pad annihilates.
  const int qbase = qt * 256 + wave * 64;
  bf16x8 qb[4][3];
#pragma unroll
  for (int t = 0; t < 4; ++t)
#pragma unroll
    for (int kk = 0; kk < 3; ++kk)
      qb[t][kk] = *(const bf16x8*)&qkv[(size_t)(b * SEQ + qbase + t * 16 + r) * QOUT +
                                       h * DH + kk * 32 + quad * 8];

  f32x4 o_acc[6][4];                         // [5] = l accumulator (ones rows)
#pragma unroll
  for (int i = 0; i < 6; ++i)
#pragma unroll
    for (int t = 0; t < 4; ++t) o_acc[i][t] = f32x4{0.f, 0.f, 0.f, 0.f};

  const unsigned short* kp = Kp + (size_t)((b * NKV + kvh) * NT64) * KTILE_ELEMS;
  const unsigned short* vp = Vp + (size_t)((b * NKV + kvh) * NT64) * VTILE_ELEMS;

  for (int kt = 0; kt < NT64; ++kt) {
    __syncthreads();
#pragma unroll
    for (int j = 0; j < 3; ++j)
      async_copy16(kp + (size_t)kt * KTILE_ELEMS + (tid + j * 256) * 8,
                   &Ks[(tid + j * 256) * 8]);
#pragma unroll
    for (int j = 0; j < 3; ++j) {
      int c = tid + j * 256;
      if (c < 640)
        async_copy16(vp + (size_t)kt * VTILE_ELEMS + c * 8, &Vs[c * 8]);
    }
    __syncthreads();

    // per-32-key pipeline: 2x QK tile -> exp2 -> pack bf16x8 -> x32 PV
#pragma unroll
    for (int ntp = 0; ntp < 2; ++ntp) {
      uint4 pw[4];
      {
        bf16x8 ka[3];
#pragma unroll
        for (int kk = 0; kk < 3; ++kk)
          ka[kk] = *(const bf16x8*)&Ks[(ntp * 32 + r) * 96 + kk * 32 + sq8];
#pragma unroll
        for (int t = 0; t < 4; ++t) {
          f32x4 s = f32x4{0.f, 0.f, 0.f, 0.f};
#pragma unroll
          for (int kk = 0; kk < 3; ++kk)
            s = __builtin_amdgcn_mfma_f32_16x16x32_bf16(ka[kk], qb[t][kk], s, 0, 0, 0);
          pw[t].x = packbf_t(exp2x(s[0]), exp2x(s[1]));
          pw[t].y = packbf_t(exp2x(s[2]), exp2x(s[3]));
        }
      }
      {
        bf16x8 ka[3];
#pragma unroll
        for (int kk = 0; kk < 3; ++kk)
          ka[kk] = *(const bf16x8*)&Ks[(ntp * 32 + 16 + r) * 96 + kk * 32 + sq8];
#pragma unroll
        for (int t = 0; t < 4; ++t) {
          f32x4 s = f32x4{0.f, 0.f, 0.f, 0.f};
#pragma unroll
          for (int kk = 0; kk < 3; ++kk)
            s = __builtin_amdgcn_mfma_f32_16x16x32_bf16(ka[kk], qb[t][kk], s, 0, 0, 0);
          pw[t].z = packbf_t(exp2x(s[0]), exp2x(s[1]));
          pw[t].w = packbf_t(exp2x(s[2]), exp2x(s[3]));
        }
      }

      // O^T += V^T(:, 32 keys) * P^T : A-frag = b128 swizzled read, floor banks
#pragma unroll
      for (int nt2 = 0; nt2 < 6; ++nt2) {
        bf16x8 va = *(const bf16x8*)&Vs[(nt2 * 16 + r) * 64 +
                                        (((ntp * 4 + quad) ^ (r & 7)) << 3)];
#pragma unroll
        for (int t = 0; t < 4; ++t) {
          union { uint4 u; bf16x8 v; } pv; pv.u = pw[t];
          o_acc[nt2][t] = __builtin_amdgcn_mfma_f32_16x16x32_bf16(va, pv.v, o_acc[nt2][t], 0, 0, 0);
        }
      }
    }
  }

#pragma unroll
  for (int t = 0; t < 4; ++t) {
    const float il = 1.0f / o_acc[5][t][0];   // l(q): all ones-rows identical
    const size_t q = (size_t)(b * SEQ + qbase + t * 16 + r);
#pragma unroll
    for (int nt2 = 0; nt2 < 5; ++nt2) {
      uint2 w;
      w.x = packbf(o_acc[nt2][t][0] * il, o_acc[nt2][t][1] * il);
      w.y = packbf(o_acc[nt2][t][2] * il, o_acc[nt2][t][3] * il);
      *(uint2*)&att[q * QSIZE + h * DH + nt2 * 16 + quad * 4] = w;
    }
  }
}

extern "C" void kernel_launch(void* const* d_in, const int* in_sizes, int n_in,
                              void* d_out, int out_size, void* d_ws, size_t ws_size,
                              hipStream_t stream) {
  const float* hs      = (const float*)d_in[0];
  const float* scaling = (const float*)d_in[1];
  const float* qkv_w   = (const float*)d_in[2];
  const float* qkv_b   = (const float*)d_in[3];
  const float* o_w     = (const float*)d_in[4];
  const float* o_b     = (const float*)d_in[5];

  char* p = (char*)d_ws;
  unsigned short* hs_bf   = (unsigned short*)p; p += (size_t)MTOT * HIDDEN * 2;
  unsigned short* qkvw_bf = (unsigned short*)p; p += (size_t)QOUT * HIDDEN * 2;
  unsigned short* ow_bf   = (unsigned short*)p; p += (size_t)HIDDEN * QSIZE * 2;
  float* cscale           = (float*)p;          p += (size_t)QOUT * 4;
  unsigned short* qkv     = (unsigned short*)p; p += (size_t)MTOT * QOUT * 2;
  unsigned short* Kp      = (unsigned short*)p; p += (size_t)BATCH * NKV * NT64 * KTILE_ELEMS * 2;
  unsigned short* Vp      = (unsigned short*)p; p += (size_t)BATCH * NKV * NT64 * VTILE_ELEMS * 2;
  unsigned short* att     = hs_bf;  // overlay: hs_bf dead after gemm1

  prep_k<<<HSB + QWB + OWB + 8, 256, 0, stream>>>(hs, qkv_w, o_w, scaling,
                                                  hs_bf, qkvw_bf, ow_bf, cscale);

  dim3 g1(QOUT / 128, MTOT / 256);
  gemm_bt<true, true><<<g1, 512, 0, stream>>>(hs_bf, qkvw_bf, qkv_b, cscale, qkv,
                                              MTOT, QOUT, HIDDEN);
  dim3 gp(NT64, NKV, BATCH);
  kvpack<<<gp, 256, 0, stream>>>(qkv, Kp, Vp);
  dim3 g3(SEQ / 256, NHEAD, BATCH);
  attn<<<g3, 256, 0, stream>>>(qkv, Kp, Vp, att);
  dim3 g4(QSIZE / 128, MTOT / 256);
  gemm_bt<false, false><<<g4, 512, 0, stream>>>(att, ow_bf, o_b, nullptr, d_out,
                                                MTOT, QSIZE, HIDDEN);
}

// Round 2
// 278.250 us; speedup vs baseline: 1.0798x; 1.0191x over previous
//
#include <hip/hip_runtime.h>

#define HIDDEN 1280
#define QOUT   1920
#define QSIZE  1280
#define KVSIZE 320
#define NHEAD  16
#define NKV    4
#define DH     80
#define SEQ    2048
#define BATCH  4
#define MTOT   (BATCH * SEQ)   // 8192
#define NT64   (SEQ / 64)      // 32 key tiles
#define KTILE_ELEMS 6144       // 64 x 96 (swizzled chunk layout)
#define VTILE_ELEMS 5120       // 80 d x 64 key (XOR-chunk swizzled)

typedef __attribute__((ext_vector_type(8))) short bf16x8;
typedef __attribute__((ext_vector_type(4))) short bf16x4;
typedef __attribute__((ext_vector_type(4))) float f32x4;

__device__ __forceinline__ unsigned short f2bf(float x) {
  union { float f; unsigned u; } v; v.f = x;
  unsigned r = v.u + 0x7fffu + ((v.u >> 16) & 1u);
  return (unsigned short)(r >> 16);
}

// round-half-up pack of two f32 -> bf16x2 (lo=a, hi=b)
__device__ __forceinline__ unsigned packbf(float a, float b) {
  union { float f; unsigned u; } ua, ub;
  ua.f = a; ub.f = b;
  return __builtin_amdgcn_perm(ub.u + 0x8000u, ua.u + 0x8000u, 0x07060302u);
}

// truncating pack (1 v_perm): fine for P (downward bias cancels via l-normalization)
__device__ __forceinline__ unsigned packbf_t(float a, float b) {
  union { float f; unsigned u; } ua, ub;
  ua.f = a; ub.f = b;
  return __builtin_amdgcn_perm(ub.u, ua.u, 0x07060302u);
}

__device__ __forceinline__ float exp2x(float x) {
#if __has_builtin(__builtin_amdgcn_exp2f)
  return __builtin_amdgcn_exp2f(x);
#else
  return exp2f(x);
#endif
}

__device__ __forceinline__ void async_copy16(const void* g, void* lds) {
  __builtin_amdgcn_global_load_lds(
      (const __attribute__((address_space(1))) unsigned int*)g,
      (__attribute__((address_space(3))) unsigned int*)lds, 16, 0, 0);
}

// ---------------- fused prep: 3x fp32->bf16 cast + colscale ----------------
#define HSB   (MTOT * HIDDEN / 4 / 256)        // 10240
#define QWB   (QOUT * HIDDEN / 4 / 256)        // 2400
#define OWB   (HIDDEN * QSIZE / 4 / 256)       // 1600
__global__ __launch_bounds__(256) void prep_k(const float* __restrict__ hs,
                                              const float* __restrict__ qkv_w,
                                              const float* __restrict__ o_w,
                                              const float* __restrict__ scaling,
                                              unsigned short* __restrict__ hs_bf,
                                              unsigned short* __restrict__ qkvw_bf,
                                              unsigned short* __restrict__ ow_bf,
                                              float* __restrict__ cs) {
  const int bid = blockIdx.x, tid = threadIdx.x;
  const float* src; unsigned short* dst; int i;
  if (bid < HSB)            { src = hs;    dst = hs_bf;   i = bid * 256 + tid; }
  else if (bid < HSB + QWB) { src = qkv_w; dst = qkvw_bf; i = (bid - HSB) * 256 + tid; }
  else if (bid < HSB + QWB + OWB) { src = o_w; dst = ow_bf; i = (bid - HSB - QWB) * 256 + tid; }
  else {
    int n = (bid - HSB - QWB - OWB) * 256 + tid;
    if (n < QOUT) {
      float v = 1.0f;
      if (n < QSIZE) {
        float x = scaling[n % DH];
        float sp = (x > 20.f) ? x : log1pf(__expf(x));
        v = 1.442695041f * 1.442695041f * 0.11180339887f * sp;  // incl. log2(e)
      }
      cs[n] = v;
    }
    return;
  }
  float4 v = ((const float4*)src)[i];
  ushort4 o;
  o.x = f2bf(v.x); o.y = f2bf(v.y); o.z = f2bf(v.z); o.w = f2bf(v.w);
  ((ushort4*)dst)[i] = o;
}

// ---------------- 256x128 bf16 MFMA GEMM, BK=64, 512 threads ----------------
template <bool OUT_BF16, bool USE_SCALE>
__global__ __launch_bounds__(512) void gemm_bt(const unsigned short* __restrict__ A,
                                               const unsigned short* __restrict__ Bt,
                                               const float* __restrict__ bias,
                                               const float* __restrict__ colscale,
                                               void* __restrict__ Cout,
                                               int M, int N, int K) {
  __shared__ unsigned short As[256 * 64];
  __shared__ unsigned short Bs[128 * 64];
  const int tid  = threadIdx.x;
  const int wave = tid >> 6, lane = tid & 63;
  const int r = lane & 15, quad = lane >> 4;
  const int xm = r & 7;
  const int m0 = blockIdx.y * 256, n0 = blockIdx.x * 128;
  const int rm = (wave >> 1) * 64, cn = (wave & 1) * 64;

  f32x4 acc[4][4];
#pragma unroll
  for (int i = 0; i < 4; ++i)
#pragma unroll
    for (int j = 0; j < 4; ++j) acc[i][j] = f32x4{0.f, 0.f, 0.f, 0.f};

  for (int k0 = 0; k0 < K; k0 += 64) {
    __syncthreads();
#pragma unroll
    for (int j = 0; j < 4; ++j) {                 // As: 2048 chunks
      const int c = tid + j * 512;
      const int row = c >> 3, sp = c & 7;
      const int sd = (sp ^ (row & 7)) * 8;
      async_copy16(A + (size_t)(m0 + row) * K + k0 + sd, &As[c * 8]);
    }
#pragma unroll
    for (int j = 0; j < 2; ++j) {                 // Bs: 1024 chunks
      const int c = tid + j * 512;
      const int row = c >> 3, sp = c & 7;
      const int sd = (sp ^ (row & 7)) * 8;
      async_copy16(Bt + (size_t)(n0 + row) * K + k0 + sd, &Bs[c * 8]);
    }
    __syncthreads();
#pragma unroll
    for (int kk = 0; kk < 2; ++kk) {
      bf16x8 af[4], bfr[4];
#pragma unroll
      for (int mi = 0; mi < 4; ++mi)
        af[mi] = *(const bf16x8*)&As[(rm + mi * 16 + r) * 64 + ((kk * 4 + quad) ^ xm) * 8];
#pragma unroll
      for (int ni = 0; ni < 4; ++ni)
        bfr[ni] = *(const bf16x8*)&Bs[(cn + ni * 16 + r) * 64 + ((kk * 4 + quad) ^ xm) * 8];
#pragma unroll
      for (int mi = 0; mi < 4; ++mi)
#pragma unroll
        for (int ni = 0; ni < 4; ++ni)
          acc[mi][ni] = __builtin_amdgcn_mfma_f32_16x16x32_bf16(af[mi], bfr[ni], acc[mi][ni], 0, 0, 0);
    }
  }

#pragma unroll
  for (int ni = 0; ni < 4; ++ni) {
    const int n = n0 + cn + ni * 16 + r;
    const float bn = bias[n];
    const float sc = USE_SCALE ? colscale[n] : 1.0f;
#pragma unroll
    for (int mi = 0; mi < 4; ++mi) {
#pragma unroll
      for (int reg = 0; reg < 4; ++reg) {
        const int m = m0 + rm + mi * 16 + quad * 4 + reg;
        const float v = (acc[mi][ni][reg] + bn) * sc;
        if (OUT_BF16)
          ((unsigned short*)Cout)[(size_t)m * N + n] = f2bf(v);
        else
          ((float*)Cout)[(size_t)m * N + n] = v;
      }
    }
  }
}

// ---------------- merged K pack (swizzled + PAIR-INTERLEAVED rows) + V pack ----
// K rows are permuted so that two consecutive 16-key QK tiles deliver each lane
// keys quad*8+{0..7} of a 32-key group -- exactly the B-fragment layout of
// mfma_16x16x32, letting PV run at full-K rate with P still register-resident.
//   Kp row -> physical key: (row>>5)*32 + ((row>>2)&3)*8 + ((row>>4)&1)*4 + (row&3)
// V image: [80 d][64 key], 8-key chunks XOR-swizzled by (d&7).
__global__ __launch_bounds__(256) void kvpack(const unsigned short* __restrict__ qkv,
                                              unsigned short* __restrict__ Kp,
                                              unsigned short* __restrict__ Vp) {
  const int st = blockIdx.x, kvh = blockIdx.y, b = blockIdx.z;
  const int tid = threadIdx.x;
  unsigned short* kout = Kp + (size_t)((b * NKV + kvh) * NT64 + st) * KTILE_ELEMS;
#pragma unroll
  for (int j = 0; j < 3; ++j) {
    int c = tid + j * 256;                  // phys chunk 0..767
    int row = c / 12, cir = c - row * 12;
    int kk = cir >> 2, sp = cir & 3;
    int sd = sp ^ ((row >> 1) & 3);
    int d0 = kk * 32 + sd * 8;
    // pair-interleave permutation: Kp row -> source key
    int skey = (row >> 5) * 32 + ((row >> 2) & 3) * 8 + ((row >> 4) & 1) * 4 + (row & 3);
    uint4 v = {0, 0, 0, 0};
    if (d0 < DH)
      v = *(const uint4*)&qkv[(size_t)(b * SEQ + st * 64 + skey) * QOUT +
                              QSIZE + kvh * DH + d0];
    *(uint4*)&kout[row * 96 + kk * 32 + sp * 8] = v;
  }
  // V transpose -> [80 d][64 key], key-chunk XOR swizzle by d&7
  __shared__ unsigned short tile[64][88];
  for (int c = tid; c < 640; c += 256) {
    int row = c / 10, seg = c % 10;
    uint4 v = *(const uint4*)&qkv[(size_t)(b * SEQ + st * 64 + row) * QOUT +
                                  QSIZE + KVSIZE + kvh * DH + seg * 8];
    *(uint4*)&tile[row][seg * 8] = v;
  }
  __syncthreads();
  unsigned short* vout = Vp + (size_t)((b * NKV + kvh) * NT64 + st) * VTILE_ELEMS;
  for (int c = tid; c < 5120; c += 256) {
    int d = c >> 6, key = c & 63;
    vout[d * 64 + (key ^ ((d & 7) << 3))] = tile[key][d];
  }
}

// ---------------- flash attention v5: 8 waves + double-buffered K/V ----------
// 512 threads (8 waves x 32 q rows): 4 waves/SIMD instead of 2, so the serial
// QK -> exp2 -> pack -> PV chain of one wave overlaps with 3 others.
// K/V LDS double-buffered; tile kt+1's DMA is issued BEFORE computing tile kt,
// so the single trailing __syncthreads' implicit vmcnt(0) drain waits on loads
// that already had the whole compute phase in flight (drain ~free; one barrier
// per kt instead of issue->drain->compute serialization).
__global__ __launch_bounds__(512, 4) void attn(const unsigned short* __restrict__ qkv,
                                               const unsigned short* __restrict__ Kp,
                                               const unsigned short* __restrict__ Vp,
                                               unsigned short* __restrict__ att) {
  const int qt = blockIdx.x, h = blockIdx.y, b = blockIdx.z;
  const int kvh = h >> 2;
  const int tid = threadIdx.x;
  const int wave = tid >> 6, lane = tid & 63;
  const int r = lane & 15, quad = lane >> 4;
  const int sq8 = (quad ^ ((r >> 1) & 3)) * 8;

  __shared__ unsigned short Ks[2][64 * 96];   // swizzled image, b128 bank floor
  __shared__ unsigned short Vs[2][96 * 64];   // [d][key] chunk-swizzled; rows 80..95 = 1.0

  // one-time ones rows in BOTH buffers (DMA only ever writes rows 0..79);
  // all-ones is invariant under the key-chunk swizzle.
  {
    const uint4 ones = {0x3F803F80u, 0x3F803F80u, 0x3F803F80u, 0x3F803F80u};
    for (int c = tid; c < 256; c += 512)
      *(uint4*)&Vs[c >> 7][80 * 64 + (c & 127) * 8] = ones;
  }

  // Q fragments straight from global (once). d>=80 lanes read neighbor data
  // that K's zero-pad annihilates.
  const int qbase = qt * 256 + wave * 32;
  bf16x8 qb[2][3];
#pragma unroll
  for (int t = 0; t < 2; ++t)
#pragma unroll
    for (int kk = 0; kk < 3; ++kk)
      qb[t][kk] = *(const bf16x8*)&qkv[(size_t)(b * SEQ + qbase + t * 16 + r) * QOUT +
                                       h * DH + kk * 32 + quad * 8];

  f32x4 o_acc[6][2];                         // [5] = l accumulator (ones rows)
#pragma unroll
  for (int i = 0; i < 6; ++i)
#pragma unroll
    for (int t = 0; t < 2; ++t) o_acc[i][t] = f32x4{0.f, 0.f, 0.f, 0.f};

  const unsigned short* kp = Kp + (size_t)((b * NKV + kvh) * NT64) * KTILE_ELEMS;
  const unsigned short* vp = Vp + (size_t)((b * NKV + kvh) * NT64) * VTILE_ELEMS;

#define STAGE(bufi, kt_) do {                                                   \
    const unsigned short* kpt = kp + (size_t)(kt_) * KTILE_ELEMS;               \
    async_copy16(kpt + tid * 8, &Ks[bufi][tid * 8]);                            \
    if (tid < 256) async_copy16(kpt + (tid + 512) * 8, &Ks[bufi][(tid + 512) * 8]); \
    const unsigned short* vpt = vp + (size_t)(kt_) * VTILE_ELEMS;               \
    async_copy16(vpt + tid * 8, &Vs[bufi][tid * 8]);                            \
    if (tid < 128) async_copy16(vpt + (tid + 512) * 8, &Vs[bufi][(tid + 512) * 8]); \
  } while (0)

  STAGE(0, 0);
  __syncthreads();                            // tile 0 + ones rows published

  for (int kt = 0; kt < NT64; ++kt) {
    const int cur = kt & 1;
    if (kt + 1 < NT64) STAGE(cur ^ 1, kt + 1);   // in flight during compute

    // per-32-key pipeline: 2x QK tile -> exp2 -> pack bf16x8 -> x32 PV
#pragma unroll
    for (int ntp = 0; ntp < 2; ++ntp) {
      uint4 pw[2];
      {
        bf16x8 ka[3];
#pragma unroll
        for (int kk = 0; kk < 3; ++kk)
          ka[kk] = *(const bf16x8*)&Ks[cur][(ntp * 32 + r) * 96 + kk * 32 + sq8];
#pragma unroll
        for (int t = 0; t < 2; ++t) {
          f32x4 s = f32x4{0.f, 0.f, 0.f, 0.f};
#pragma unroll
          for (int kk = 0; kk < 3; ++kk)
            s = __builtin_amdgcn_mfma_f32_16x16x32_bf16(ka[kk], qb[t][kk], s, 0, 0, 0);
          pw[t].x = packbf_t(exp2x(s[0]), exp2x(s[1]));
          pw[t].y = packbf_t(exp2x(s[2]), exp2x(s[3]));
        }
      }
      {
        bf16x8 ka[3];
#pragma unroll
        for (int kk = 0; kk < 3; ++kk)
          ka[kk] = *(const bf16x8*)&Ks[cur][(ntp * 32 + 16 + r) * 96 + kk * 32 + sq8];
#pragma unroll
        for (int t = 0; t < 2; ++t) {
          f32x4 s = f32x4{0.f, 0.f, 0.f, 0.f};
#pragma unroll
          for (int kk = 0; kk < 3; ++kk)
            s = __builtin_amdgcn_mfma_f32_16x16x32_bf16(ka[kk], qb[t][kk], s, 0, 0, 0);
          pw[t].z = packbf_t(exp2x(s[0]), exp2x(s[1]));
          pw[t].w = packbf_t(exp2x(s[2]), exp2x(s[3]));
        }
      }

      // O^T += V^T(:, 32 keys) * P^T : A-frag = b128 swizzled read, floor banks
#pragma unroll
      for (int nt2 = 0; nt2 < 6; ++nt2) {
        bf16x8 va = *(const bf16x8*)&Vs[cur][(nt2 * 16 + r) * 64 +
                                             (((ntp * 4 + quad) ^ (r & 7)) << 3)];
#pragma unroll
        for (int t = 0; t < 2; ++t) {
          union { uint4 u; bf16x8 v; } pv; pv.u = pw[t];
          o_acc[nt2][t] = __builtin_amdgcn_mfma_f32_16x16x32_bf16(va, pv.v, o_acc[nt2][t], 0, 0, 0);
        }
      }
    }
    __syncthreads();   // implicit vmcnt(0): kt+1 loads had full compute to land;
                       // also fences reads of buf[cur] before it is re-staged
  }
#undef STAGE

#pragma unroll
  for (int t = 0; t < 2; ++t) {
    const float il = 1.0f / o_acc[5][t][0];   // l(q): all ones-rows identical
    const size_t q = (size_t)(b * SEQ + qbase + t * 16 + r);
#pragma unroll
    for (int nt2 = 0; nt2 < 5; ++nt2) {
      uint2 w;
      w.x = packbf(o_acc[nt2][t][0] * il, o_acc[nt2][t][1] * il);
      w.y = packbf(o_acc[nt2][t][2] * il, o_acc[nt2][t][3] * il);
      *(uint2*)&att[q * QSIZE + h * DH + nt2 * 16 + quad * 4] = w;
    }
  }
}

extern "C" void kernel_launch(void* const* d_in, const int* in_sizes, int n_in,
                              void* d_out, int out_size, void* d_ws, size_t ws_size,
                              hipStream_t stream) {
  const float* hs      = (const float*)d_in[0];
  const float* scaling = (const float*)d_in[1];
  const float* qkv_w   = (const float*)d_in[2];
  const float* qkv_b   = (const float*)d_in[3];
  const float* o_w     = (const float*)d_in[4];
  const float* o_b     = (const float*)d_in[5];

  char* p = (char*)d_ws;
  unsigned short* hs_bf   = (unsigned short*)p; p += (size_t)MTOT * HIDDEN * 2;
  unsigned short* qkvw_bf = (unsigned short*)p; p += (size_t)QOUT * HIDDEN * 2;
  unsigned short* ow_bf   = (unsigned short*)p; p += (size_t)HIDDEN * QSIZE * 2;
  float* cscale           = (float*)p;          p += (size_t)QOUT * 4;
  unsigned short* qkv     = (unsigned short*)p; p += (size_t)MTOT * QOUT * 2;
  unsigned short* Kp      = (unsigned short*)p; p += (size_t)BATCH * NKV * NT64 * KTILE_ELEMS * 2;
  unsigned short* Vp      = (unsigned short*)p; p += (size_t)BATCH * NKV * NT64 * VTILE_ELEMS * 2;
  unsigned short* att     = hs_bf;  // overlay: hs_bf dead after gemm1

  prep_k<<<HSB + QWB + OWB + 8, 256, 0, stream>>>(hs, qkv_w, o_w, scaling,
                                                  hs_bf, qkvw_bf, ow_bf, cscale);

  dim3 g1(QOUT / 128, MTOT / 256);
  gemm_bt<true, true><<<g1, 512, 0, stream>>>(hs_bf, qkvw_bf, qkv_b, cscale, qkv,
                                              MTOT, QOUT, HIDDEN);
  dim3 gp(NT64, NKV, BATCH);
  kvpack<<<gp, 256, 0, stream>>>(qkv, Kp, Vp);
  dim3 g3(SEQ / 256, NHEAD, BATCH);
  attn<<<g3, 512, 0, stream>>>(qkv, Kp, Vp, att);
  dim3 g4(QSIZE / 128, MTOT / 256);
  gemm_bt<false, false><<<g4, 512, 0, stream>>>(att, ow_bf, o_b, nullptr, d_out,
                                                MTOT, QSIZE, HIDDEN);
}

// Round 3
// 275.007 us; speedup vs baseline: 1.0925x; 1.0118x over previous
//
#include <hip/hip_runtime.h>

#define HIDDEN 1280
#define QOUT   1920
#define QSIZE  1280
#define KVSIZE 320
#define NHEAD  16
#define NKV    4
#define DH     80
#define SEQ    2048
#define BATCH  4
#define MTOT   (BATCH * SEQ)   // 8192
#define NT64   (SEQ / 64)      // 32 key tiles
#define KTILE_ELEMS 6144       // 64 x 96 (swizzled chunk layout)
#define VTILE_ELEMS 5120       // 80 d x 64 key (XOR-chunk swizzled)

typedef __attribute__((ext_vector_type(8))) short bf16x8;
typedef __attribute__((ext_vector_type(4))) short bf16x4;
typedef __attribute__((ext_vector_type(4))) float f32x4;

__device__ __forceinline__ unsigned short f2bf(float x) {
  union { float f; unsigned u; } v; v.f = x;
  unsigned r = v.u + 0x7fffu + ((v.u >> 16) & 1u);
  return (unsigned short)(r >> 16);
}

// round-half-up pack of two f32 -> bf16x2 (lo=a, hi=b)
__device__ __forceinline__ unsigned packbf(float a, float b) {
  union { float f; unsigned u; } ua, ub;
  ua.f = a; ub.f = b;
  return __builtin_amdgcn_perm(ub.u + 0x8000u, ua.u + 0x8000u, 0x07060302u);
}

// truncating pack (1 v_perm): fine for P (downward bias cancels via l-normalization)
__device__ __forceinline__ unsigned packbf_t(float a, float b) {
  union { float f; unsigned u; } ua, ub;
  ua.f = a; ub.f = b;
  return __builtin_amdgcn_perm(ub.u, ua.u, 0x07060302u);
}

__device__ __forceinline__ float exp2x(float x) {
#if __has_builtin(__builtin_amdgcn_exp2f)
  return __builtin_amdgcn_exp2f(x);
#else
  return exp2f(x);
#endif
}

__device__ __forceinline__ void async_copy16(const void* g, void* lds) {
  __builtin_amdgcn_global_load_lds(
      (const __attribute__((address_space(1))) unsigned int*)g,
      (__attribute__((address_space(3))) unsigned int*)lds, 16, 0, 0);
}

// ---------------- fused prep: 3x fp32->bf16 cast + colscale ----------------
#define HSB   (MTOT * HIDDEN / 4 / 256)        // 10240
#define QWB   (QOUT * HIDDEN / 4 / 256)        // 2400
#define OWB   (HIDDEN * QSIZE / 4 / 256)       // 1600
__global__ __launch_bounds__(256) void prep_k(const float* __restrict__ hs,
                                              const float* __restrict__ qkv_w,
                                              const float* __restrict__ o_w,
                                              const float* __restrict__ scaling,
                                              unsigned short* __restrict__ hs_bf,
                                              unsigned short* __restrict__ qkvw_bf,
                                              unsigned short* __restrict__ ow_bf,
                                              float* __restrict__ cs) {
  const int bid = blockIdx.x, tid = threadIdx.x;
  const float* src; unsigned short* dst; int i;
  if (bid < HSB)            { src = hs;    dst = hs_bf;   i = bid * 256 + tid; }
  else if (bid < HSB + QWB) { src = qkv_w; dst = qkvw_bf; i = (bid - HSB) * 256 + tid; }
  else if (bid < HSB + QWB + OWB) { src = o_w; dst = ow_bf; i = (bid - HSB - QWB) * 256 + tid; }
  else {
    int n = (bid - HSB - QWB - OWB) * 256 + tid;
    if (n < QOUT) {
      float v = 1.0f;
      if (n < QSIZE) {
        float x = scaling[n % DH];
        float sp = (x > 20.f) ? x : log1pf(__expf(x));
        v = 1.442695041f * 1.442695041f * 0.11180339887f * sp;  // incl. log2(e)
      }
      cs[n] = v;
    }
    return;
  }
  float4 v = ((const float4*)src)[i];
  ushort4 o;
  o.x = f2bf(v.x); o.y = f2bf(v.y); o.z = f2bf(v.z); o.w = f2bf(v.w);
  ((ushort4*)dst)[i] = o;
}

// ---------------- 256x128 bf16 MFMA GEMM, BK=64, 512 threads ----------------
// XCD-chunked block swizzle: blocks resident on one XCD cover a contiguous
// band of (m,n) tiles -> A/B panel reuse hits that XCD's private L2.
template <bool OUT_BF16, bool USE_SCALE>
__global__ __launch_bounds__(512) void gemm_bt(const unsigned short* __restrict__ A,
                                               const unsigned short* __restrict__ Bt,
                                               const float* __restrict__ bias,
                                               const float* __restrict__ colscale,
                                               void* __restrict__ Cout,
                                               int M, int N, int K) {
  __shared__ unsigned short As[256 * 64];
  __shared__ unsigned short Bs[128 * 64];
  const int tid  = threadIdx.x;
  const int wave = tid >> 6, lane = tid & 63;
  const int r = lane & 15, quad = lane >> 4;
  const int xm = r & 7;
  // bijective chunked XCD swizzle (grid sizes here are multiples of 8)
  const int gx = gridDim.x;
  int lid = blockIdx.y * gx + blockIdx.x;
  const int cpx = (gx * gridDim.y) >> 3;
  lid = (lid & 7) * cpx + (lid >> 3);
  const int m0 = (lid / gx) * 256, n0 = (lid % gx) * 128;
  const int rm = (wave >> 1) * 64, cn = (wave & 1) * 64;

  f32x4 acc[4][4];
#pragma unroll
  for (int i = 0; i < 4; ++i)
#pragma unroll
    for (int j = 0; j < 4; ++j) acc[i][j] = f32x4{0.f, 0.f, 0.f, 0.f};

  for (int k0 = 0; k0 < K; k0 += 64) {
    __syncthreads();
#pragma unroll
    for (int j = 0; j < 4; ++j) {                 // As: 2048 chunks
      const int c = tid + j * 512;
      const int row = c >> 3, sp = c & 7;
      const int sd = (sp ^ (row & 7)) * 8;
      async_copy16(A + (size_t)(m0 + row) * K + k0 + sd, &As[c * 8]);
    }
#pragma unroll
    for (int j = 0; j < 2; ++j) {                 // Bs: 1024 chunks
      const int c = tid + j * 512;
      const int row = c >> 3, sp = c & 7;
      const int sd = (sp ^ (row & 7)) * 8;
      async_copy16(Bt + (size_t)(n0 + row) * K + k0 + sd, &Bs[c * 8]);
    }
    __syncthreads();
#pragma unroll
    for (int kk = 0; kk < 2; ++kk) {
      bf16x8 af[4], bfr[4];
#pragma unroll
      for (int mi = 0; mi < 4; ++mi)
        af[mi] = *(const bf16x8*)&As[(rm + mi * 16 + r) * 64 + ((kk * 4 + quad) ^ xm) * 8];
#pragma unroll
      for (int ni = 0; ni < 4; ++ni)
        bfr[ni] = *(const bf16x8*)&Bs[(cn + ni * 16 + r) * 64 + ((kk * 4 + quad) ^ xm) * 8];
#pragma unroll
      for (int mi = 0; mi < 4; ++mi)
#pragma unroll
        for (int ni = 0; ni < 4; ++ni)
          acc[mi][ni] = __builtin_amdgcn_mfma_f32_16x16x32_bf16(af[mi], bfr[ni], acc[mi][ni], 0, 0, 0);
    }
  }

#pragma unroll
  for (int ni = 0; ni < 4; ++ni) {
    const int n = n0 + cn + ni * 16 + r;
    const float bn = bias[n];
    const float sc = USE_SCALE ? colscale[n] : 1.0f;
#pragma unroll
    for (int mi = 0; mi < 4; ++mi) {
#pragma unroll
      for (int reg = 0; reg < 4; ++reg) {
        const int m = m0 + rm + mi * 16 + quad * 4 + reg;
        const float v = (acc[mi][ni][reg] + bn) * sc;
        if (OUT_BF16)
          ((unsigned short*)Cout)[(size_t)m * N + n] = f2bf(v);
        else
          ((float*)Cout)[(size_t)m * N + n] = v;
      }
    }
  }
}

// ---------------- merged K pack (swizzled + PAIR-INTERLEAVED rows) + V pack ----
// K rows are permuted so that two consecutive 16-key QK tiles deliver each lane
// keys quad*8+{0..7} of a 32-key group -- exactly the B-fragment layout of
// mfma_16x16x32, letting PV run at full-K rate with P still register-resident.
//   Kp row -> physical key: (row>>5)*32 + ((row>>2)&3)*8 + ((row>>4)&1)*4 + (row&3)
// V image: [80 d][64 key], 8-key chunks XOR-swizzled by (d&7).
__global__ __launch_bounds__(256) void kvpack(const unsigned short* __restrict__ qkv,
                                              unsigned short* __restrict__ Kp,
                                              unsigned short* __restrict__ Vp) {
  const int st = blockIdx.x, kvh = blockIdx.y, b = blockIdx.z;
  const int tid = threadIdx.x;
  unsigned short* kout = Kp + (size_t)((b * NKV + kvh) * NT64 + st) * KTILE_ELEMS;
#pragma unroll
  for (int j = 0; j < 3; ++j) {
    int c = tid + j * 256;                  // phys chunk 0..767
    int row = c / 12, cir = c - row * 12;
    int kk = cir >> 2, sp = cir & 3;
    int sd = sp ^ ((row >> 1) & 3);
    int d0 = kk * 32 + sd * 8;
    // pair-interleave permutation: Kp row -> source key
    int skey = (row >> 5) * 32 + ((row >> 2) & 3) * 8 + ((row >> 4) & 1) * 4 + (row & 3);
    uint4 v = {0, 0, 0, 0};
    if (d0 < DH)
      v = *(const uint4*)&qkv[(size_t)(b * SEQ + st * 64 + skey) * QOUT +
                              QSIZE + kvh * DH + d0];
    *(uint4*)&kout[row * 96 + kk * 32 + sp * 8] = v;
  }
  // V transpose -> [80 d][64 key], key-chunk XOR swizzle by d&7
  __shared__ unsigned short tile[64][88];
  for (int c = tid; c < 640; c += 256) {
    int row = c / 10, seg = c % 10;
    uint4 v = *(const uint4*)&qkv[(size_t)(b * SEQ + st * 64 + row) * QOUT +
                                  QSIZE + KVSIZE + kvh * DH + seg * 8];
    *(uint4*)&tile[row][seg * 8] = v;
  }
  __syncthreads();
  unsigned short* vout = Vp + (size_t)((b * NKV + kvh) * NT64 + st) * VTILE_ELEMS;
  for (int c = tid; c < 5120; c += 256) {
    int d = c >> 6, key = c & 63;
    vout[d * 64 + (key ^ ((d & 7) << 3))] = tile[key][d];
  }
}

// ---------------- flash attention v6: phase-split QK||exp||PV pipeline -------
// Per kt: ALL 24 QK MFMAs first (one long matrix burst into s[2][2][2]), then
// per 32-key chunk {exp2/pack (VALU), PV (MFMA)}. The issue stream
// [QK][exp0][PV0][exp1][PV1] lets each VALU phase issue while the previous
// MFMA burst drains in the pipe -- within-wave MFMA/VALU overlap (R2 showed
// TLP alone leaves MfmaUtil at 48% with pipes serialized in lockstep).
// setprio(1) wraps the MFMA bursts (T5): waves in a matrix burst win
// arbitration over co-resident waves doing exp2/addressing.
__global__ __launch_bounds__(512, 4) void attn(const unsigned short* __restrict__ qkv,
                                               const unsigned short* __restrict__ Kp,
                                               const unsigned short* __restrict__ Vp,
                                               unsigned short* __restrict__ att) {
  // XCD-chunked swizzle: 32 blocks share each 720KB K/V stream; make them
  // co-resident on one XCD's L2 instead of round-robined across all 8.
  int qt, h, b;
  {
    int lid = (blockIdx.z * 16 + blockIdx.y) * 8 + blockIdx.x;   // 512 blocks
    lid = (lid & 7) * 64 + (lid >> 3);
    qt = lid & 7; h = (lid >> 3) & 15; b = lid >> 7;
  }
  const int kvh = h >> 2;
  const int tid = threadIdx.x;
  const int wave = tid >> 6, lane = tid & 63;
  const int r = lane & 15, quad = lane >> 4;
  const int sq8 = (quad ^ ((r >> 1) & 3)) * 8;

  __shared__ unsigned short Ks[2][64 * 96];   // swizzled image, b128 bank floor
  __shared__ unsigned short Vs[2][96 * 64];   // [d][key] chunk-swizzled; rows 80..95 = 1.0

  // one-time ones rows in BOTH buffers (DMA only ever writes rows 0..79);
  // all-ones is invariant under the key-chunk swizzle.
  {
    const uint4 ones = {0x3F803F80u, 0x3F803F80u, 0x3F803F80u, 0x3F803F80u};
    for (int c = tid; c < 256; c += 512)
      *(uint4*)&Vs[c >> 7][80 * 64 + (c & 127) * 8] = ones;
  }

  // Q fragments straight from global (once). d>=80 lanes read neighbor data
  // that K's zero-pad annihilates.
  const int qbase = qt * 256 + wave * 32;
  bf16x8 qb[2][3];
#pragma unroll
  for (int t = 0; t < 2; ++t)
#pragma unroll
    for (int kk = 0; kk < 3; ++kk)
      qb[t][kk] = *(const bf16x8*)&qkv[(size_t)(b * SEQ + qbase + t * 16 + r) * QOUT +
                                       h * DH + kk * 32 + quad * 8];

  f32x4 o_acc[6][2];                         // [5] = l accumulator (ones rows)
#pragma unroll
  for (int i = 0; i < 6; ++i)
#pragma unroll
    for (int t = 0; t < 2; ++t) o_acc[i][t] = f32x4{0.f, 0.f, 0.f, 0.f};

  const unsigned short* kp = Kp + (size_t)((b * NKV + kvh) * NT64) * KTILE_ELEMS;
  const unsigned short* vp = Vp + (size_t)((b * NKV + kvh) * NT64) * VTILE_ELEMS;

#define STAGE(bufi, kt_) do {                                                   \
    const unsigned short* kpt = kp + (size_t)(kt_) * KTILE_ELEMS;               \
    async_copy16(kpt + tid * 8, &Ks[bufi][tid * 8]);                            \
    if (tid < 256) async_copy16(kpt + (tid + 512) * 8, &Ks[bufi][(tid + 512) * 8]); \
    const unsigned short* vpt = vp + (size_t)(kt_) * VTILE_ELEMS;               \
    async_copy16(vpt + tid * 8, &Vs[bufi][tid * 8]);                            \
    if (tid < 128) async_copy16(vpt + (tid + 512) * 8, &Vs[bufi][(tid + 512) * 8]); \
  } while (0)

  STAGE(0, 0);
  __syncthreads();                            // tile 0 + ones rows published

  for (int kt = 0; kt < NT64; ++kt) {
    const int cur = kt & 1;
    if (kt + 1 < NT64) STAGE(cur ^ 1, kt + 1);   // in flight during compute

    // Phase A: all QK MFMAs for this 64-key tile (24 x32) -> s[ntp][half][t]
    f32x4 s[2][2][2];
    __builtin_amdgcn_s_setprio(1);
#pragma unroll
    for (int ntp = 0; ntp < 2; ++ntp)
#pragma unroll
      for (int half = 0; half < 2; ++half) {
        bf16x8 ka[3];
#pragma unroll
        for (int kk = 0; kk < 3; ++kk)
          ka[kk] = *(const bf16x8*)&Ks[cur][(ntp * 32 + half * 16 + r) * 96 + kk * 32 + sq8];
#pragma unroll
        for (int t = 0; t < 2; ++t) {
          f32x4 a0 = f32x4{0.f, 0.f, 0.f, 0.f};
#pragma unroll
          for (int kk = 0; kk < 3; ++kk)
            a0 = __builtin_amdgcn_mfma_f32_16x16x32_bf16(ka[kk], qb[t][kk], a0, 0, 0, 0);
          s[ntp][half][t] = a0;
        }
      }
    __builtin_amdgcn_s_setprio(0);

    // Phase B/C per 32-key chunk: exp2+pack (VALU), then x32 PV (MFMA).
    // Chunk 1's VALU overlaps chunk 0's PV drain.
#pragma unroll
    for (int ntp = 0; ntp < 2; ++ntp) {
      uint4 pw[2];
#pragma unroll
      for (int t = 0; t < 2; ++t) {
        pw[t].x = packbf_t(exp2x(s[ntp][0][t][0]), exp2x(s[ntp][0][t][1]));
        pw[t].y = packbf_t(exp2x(s[ntp][0][t][2]), exp2x(s[ntp][0][t][3]));
        pw[t].z = packbf_t(exp2x(s[ntp][1][t][0]), exp2x(s[ntp][1][t][1]));
        pw[t].w = packbf_t(exp2x(s[ntp][1][t][2]), exp2x(s[ntp][1][t][3]));
      }
      __builtin_amdgcn_s_setprio(1);
#pragma unroll
      for (int nt2 = 0; nt2 < 6; ++nt2) {
        bf16x8 va = *(const bf16x8*)&Vs[cur][(nt2 * 16 + r) * 64 +
                                             (((ntp * 4 + quad) ^ (r & 7)) << 3)];
#pragma unroll
        for (int t = 0; t < 2; ++t) {
          union { uint4 u; bf16x8 v; } pv; pv.u = pw[t];
          o_acc[nt2][t] = __builtin_amdgcn_mfma_f32_16x16x32_bf16(va, pv.v, o_acc[nt2][t], 0, 0, 0);
        }
      }
      __builtin_amdgcn_s_setprio(0);
    }
    __syncthreads();   // implicit vmcnt(0): kt+1 loads had full compute to land;
                       // also fences reads of buf[cur] before it is re-staged
  }
#undef STAGE

#pragma unroll
  for (int t = 0; t < 2; ++t) {
    const float il = 1.0f / o_acc[5][t][0];   // l(q): all ones-rows identical
    const size_t q = (size_t)(b * SEQ + qbase + t * 16 + r);
#pragma unroll
    for (int nt2 = 0; nt2 < 5; ++nt2) {
      uint2 w;
      w.x = packbf(o_acc[nt2][t][0] * il, o_acc[nt2][t][1] * il);
      w.y = packbf(o_acc[nt2][t][2] * il, o_acc[nt2][t][3] * il);
      *(uint2*)&att[q * QSIZE + h * DH + nt2 * 16 + quad * 4] = w;
    }
  }
}

extern "C" void kernel_launch(void* const* d_in, const int* in_sizes, int n_in,
                              void* d_out, int out_size, void* d_ws, size_t ws_size,
                              hipStream_t stream) {
  const float* hs      = (const float*)d_in[0];
  const float* scaling = (const float*)d_in[1];
  const float* qkv_w   = (const float*)d_in[2];
  const float* qkv_b   = (const float*)d_in[3];
  const float* o_w     = (const float*)d_in[4];
  const float* o_b     = (const float*)d_in[5];

  char* p = (char*)d_ws;
  unsigned short* hs_bf   = (unsigned short*)p; p += (size_t)MTOT * HIDDEN * 2;
  unsigned short* qkvw_bf = (unsigned short*)p; p += (size_t)QOUT * HIDDEN * 2;
  unsigned short* ow_bf   = (unsigned short*)p; p += (size_t)HIDDEN * QSIZE * 2;
  float* cscale           = (float*)p;          p += (size_t)QOUT * 4;
  unsigned short* qkv     = (unsigned short*)p; p += (size_t)MTOT * QOUT * 2;
  unsigned short* Kp      = (unsigned short*)p; p += (size_t)BATCH * NKV * NT64 * KTILE_ELEMS * 2;
  unsigned short* Vp      = (unsigned short*)p; p += (size_t)BATCH * NKV * NT64 * VTILE_ELEMS * 2;
  unsigned short* att     = hs_bf;  // overlay: hs_bf dead after gemm1

  prep_k<<<HSB + QWB + OWB + 8, 256, 0, stream>>>(hs, qkv_w, o_w, scaling,
                                                  hs_bf, qkvw_bf, ow_bf, cscale);

  dim3 g1(QOUT / 128, MTOT / 256);
  gemm_bt<true, true><<<g1, 512, 0, stream>>>(hs_bf, qkvw_bf, qkv_b, cscale, qkv,
                                              MTOT, QOUT, HIDDEN);
  dim3 gp(NT64, NKV, BATCH);
  kvpack<<<gp, 256, 0, stream>>>(qkv, Kp, Vp);
  dim3 g3(SEQ / 256, NHEAD, BATCH);
  attn<<<g3, 512, 0, stream>>>(qkv, Kp, Vp, att);
  dim3 g4(QSIZE / 128, MTOT / 256);
  gemm_bt<false, false><<<g4, 512, 0, stream>>>(att, ow_bf, o_b, nullptr, d_out,
                                                MTOT, QSIZE, HIDDEN);
}